// Round 1
// baseline (316.497 us; speedup 1.0000x reference)
//
#include <hip/hip_runtime.h>

// VQ-VAE forward: x [64,64,32,32] f32 (NCHW, C==D), weight [512,64] f32.
// Outputs concatenated in d_out: loss (1) | q_out (4194304) | encodings (33554432).
// N = 64*32*32 = 65536 rows of dim 64, K = 512 codes.

#define NROWS 65536
#define DIM 64
#define KCODES 512
#define HW 1024          // H*W = 32*32
#define TPB 128          // threads per block = rows per block
#define NBLOCKS (NROWS / TPB)   // 512

typedef float v2f __attribute__((ext_vector_type(2)));

__global__ __launch_bounds__(TPB) void vq_main(
    const float* __restrict__ x,
    const float* __restrict__ w,
    float* __restrict__ out,
    float* __restrict__ partial)
{
    __shared__ float e2[KCODES];
    __shared__ int   idx_lds[TPB];
    __shared__ float lsum_lds[TPB / 64];

    const int t  = threadIdx.x;
    const int n0 = blockIdx.x * TPB;      // first row of this block
    const int b  = n0 >> 10;              // n / (H*W); block never straddles b (1024 % 128 == 0)
    const int hw = (n0 & 1023) + t;

    // ---- e2[k] = sum_d w[k][d]^2 (each thread does 4 codes); mirror XLA:
    // elementwise mul then add, NOT fma-contracted.
    #pragma unroll
    for (int c = 0; c < 4; ++c) {
        const int k = t * 4 + c;
        const float* wr = w + k * DIM;
        float s = 0.0f;
        for (int d = 0; d < DIM; ++d) s = __fadd_rn(s, __fmul_rn(wr[d], wr[d]));
        e2[k] = s;
    }

    // ---- load this thread's x row (coalesced across lanes for each d) into
    // float2 pairs for packed fp32 FMA.
    v2f xv[DIM / 2];
    {
        const float* xb = x + (size_t)(b * DIM) * HW + hw;
        #pragma unroll
        for (int i = 0; i < DIM / 2; ++i) {
            xv[i][0] = xb[(size_t)(2 * i) * HW];
            xv[i][1] = xb[(size_t)(2 * i + 1) * HW];
        }
    }

    // x2 = sum_d x_d^2, mul-then-add (no contraction)
    float x2 = 0.0f;
    #pragma unroll
    for (int i = 0; i < DIM / 2; ++i) {
        x2 = __fadd_rn(x2, __fmul_rn(xv[i][0], xv[i][0]));
        x2 = __fadd_rn(x2, __fmul_rn(xv[i][1], xv[i][1]));
    }

    __syncthreads();   // e2 ready

    // ---- argmin over codes. Inner GEMM: 4 code-accumulators, packed fp32 FMA.
    // w indices are wave-uniform -> scalar loads; xv in VGPRs.
    const v2f* w2 = (const v2f*)w;       // [K][32]
    float best = 3.4e38f;
    int   bidx = 0;
    for (int k0 = 0; k0 < KCODES; k0 += 4) {
        v2f a0 = {0.f, 0.f}, a1 = {0.f, 0.f}, a2 = {0.f, 0.f}, a3 = {0.f, 0.f};
        const v2f* wr0 = w2 + (k0 + 0) * (DIM / 2);
        const v2f* wr1 = w2 + (k0 + 1) * (DIM / 2);
        const v2f* wr2 = w2 + (k0 + 2) * (DIM / 2);
        const v2f* wr3 = w2 + (k0 + 3) * (DIM / 2);
        #pragma unroll
        for (int i = 0; i < DIM / 2; ++i) {
            const v2f xvi = xv[i];
            a0 += xvi * wr0[i];          // v_pk_fma_f32
            a1 += xvi * wr1[i];
            a2 += xvi * wr2[i];
            a3 += xvi * wr3[i];
        }
        float dots[4];
        dots[0] = a0[0] + a0[1];
        dots[1] = a1[0] + a1[1];
        dots[2] = a2[0] + a2[1];
        dots[3] = a3[0] + a3[1];
        #pragma unroll
        for (int c = 0; c < 4; ++c) {
            // mirror reference: dist = (x2 + e2[k]) - 2*dot, non-contracted
            const float dist = __fsub_rn(__fadd_rn(x2, e2[k0 + c]),
                                         __fmul_rn(2.0f, dots[c]));
            if (dist < best) { best = dist; bidx = k0 + c; }   // strict <: first-min
        }
    }

    // ---- gather codebook row: q_out store + loss partial
    idx_lds[t] = bidx;
    float* q = out + 1;                   // q_out base (flat NCHW)
    const float* wrow = w + bidx * DIM;
    float lsum = 0.0f;
    #pragma unroll
    for (int d = 0; d < DIM; ++d) {
        const float wv = wrow[d];                             // per-lane gather, L1-hot
        const float xd = xv[d >> 1][d & 1];
        const float df = __fsub_rn(wv, xd);
        lsum = __fadd_rn(lsum, __fmul_rn(df, df));
        q[(size_t)(b * DIM + d) * HW + hw] = wv;              // coalesced across lanes
    }

    // ---- block loss reduction (deterministic)
    #pragma unroll
    for (int off = 32; off; off >>= 1) lsum += __shfl_down(lsum, off, 64);
    if ((t & 63) == 0) lsum_lds[t >> 6] = lsum;
    __syncthreads();                       // also publishes idx_lds
    if (t == 0) partial[blockIdx.x] = lsum_lds[0] + lsum_lds[1];

    // ---- one-hot encodings: this block's contiguous 128x512 slab, coalesced
    float* enc = out + 1 + (size_t)NROWS * DIM;
    const size_t base = (size_t)n0 * KCODES;
    for (int i = t; i < TPB * KCODES; i += TPB) {
        const int nl = i >> 9;            // i / 512
        const int k  = i & 511;
        enc[base + i] = (idx_lds[nl] == k) ? 1.0f : 0.0f;
    }
}

__global__ __launch_bounds__(256) void vq_final(
    const float* __restrict__ partial, float* __restrict__ out)
{
    __shared__ float s[256];
    const int t = threadIdx.x;
    s[t] = partial[t] + partial[t + 256];
    __syncthreads();
    for (int off = 128; off; off >>= 1) {
        if (t < off) s[t] += s[t + off];
        __syncthreads();
    }
    if (t == 0) {
        const float m = s[0] / 4194304.0f;        // mean over B*H*W*D
        out[0] = __fadd_rn(m, __fmul_rn(0.25f, m)); // z_q + 0.25*z_e (equal in value)
    }
}

extern "C" void kernel_launch(void* const* d_in, const int* in_sizes, int n_in,
                              void* d_out, int out_size, void* d_ws, size_t ws_size,
                              hipStream_t stream) {
    const float* x = (const float*)d_in[0];
    const float* w = (const float*)d_in[1];
    float* out     = (float*)d_out;
    float* partial = (float*)d_ws;        // 512 floats of scratch

    vq_main<<<NBLOCKS, TPB, 0, stream>>>(x, w, out, partial);
    vq_final<<<1, 256, 0, stream>>>(partial, out);
}